// Round 8
// baseline (139.312 us; speedup 1.0000x reference)
//
#include <hip/hip_runtime.h>

// CausalSelfAttention: B=4 T=1024 C=768 NH=12 HD=64, start_pos=0.
// Round 22: k_attn wave-q-tile 32 -> 64 rows (aq[4], o[4][4], 4 rh-subtiles).
//   Achieves R16's staging-amortization goal WITHOUT its failure mode: still
//   2 waves/block (same barrier group), blocks 768 -> 384, chunk-stages
//   6528 -> 3456 (-47% staging/barrier/L2 re-read), K/V frags amortized over
//   2x MFMA. Wave imbalance bounded at 1 chunk (wave0: 2t+1 of 2t+2).
//   VGPR ~92 -> ~200 (2 waves/SIMD) -- fatter waves, 2x softmax/MFMA ILP.
// Round 21 (kept): k_proj 64x96, 512 blocks 2.00/CU. Round 20 (kept): Wproj
//   transpose in k_attn tail. Round 18 (kept): k_qkv 128x96, 768 blocks.
// Round 15 (kept): GEMM 2-deep LDS dbuf + counted vmcnt.
// MFMA 16x16x32 bf16 layouts (HW-verified per guide):
//   A-op:  A[m=lane&15][k=(lane>>4)*8+j]   (8 bf16 / lane, contiguous in k)
//   B-op:  B[k=(lane>>4)*8+j][n=lane&15]   (contiguous in k)
//   C/D :  C[row=(lane>>4)*4+reg][col=lane&15]

#define BB 4
#define TT 1024
#define CC 768
#define NHH 12
#define HDD 64
#define BHH (BB*NHH)

typedef unsigned short u16;
typedef __attribute__((ext_vector_type(8))) short bf16x8;
typedef __attribute__((ext_vector_type(4))) float f32x4;
typedef __attribute__((ext_vector_type(4))) int i32x4;

__device__ __forceinline__ u16 f2b(float f) {
  unsigned u = __float_as_uint(f);
  u += 0x7fffu + ((u >> 16) & 1u);   // RTNE
  return (u16)(u >> 16);
}
// pack two floats' high halves into one dword (truncating bf16; P in [0,1])
__device__ __forceinline__ unsigned packbf(float lo, float hi) {
  return (__float_as_uint(hi) & 0xffff0000u) | (__float_as_uint(lo) >> 16);
}

// async global->LDS, 16B per lane; LDS dest must be wave-uniform base + lane*16
__device__ __forceinline__ void gload_lds16(const u16* g, u16* l) {
  __builtin_amdgcn_global_load_lds(
      (const __attribute__((address_space(1))) unsigned int*)g,
      (__attribute__((address_space(3))) unsigned int*)l, 16, 0, 0);
}

// ---------- prep: x fp32->bf16 cvt  +  Wqkv transpose (Wproj in k_attn) ----------
__device__ __forceinline__ void tr_body(const float* __restrict__ in, u16* __restrict__ out,
                                        int R, int Cc, int bx, int by, float (*tile)[33]) {
  int c0 = bx * 32, r0 = by * 32;
  int tx = threadIdx.x & 31, ty = threadIdx.x >> 5;  // 32 x 8
#pragma unroll
  for (int i = 0; i < 32; i += 8)
    tile[ty + i][tx] = in[(r0 + ty + i) * Cc + c0 + tx];
  __syncthreads();
#pragma unroll
  for (int i = 0; i < 32; i += 8)
    out[(c0 + ty + i) * R + r0 + tx] = f2b(tile[tx][ty + i]);
}

__global__ __launch_bounds__(256) void k_prep(const float* __restrict__ x, u16* __restrict__ xb,
                                              const float* __restrict__ Wqkv, u16* __restrict__ Wqkv_t) {
  __shared__ float tile[32][33];
  int bid = blockIdx.x;
  if (bid < 3072) {                       // cvt: 786432 float4 groups
    int i = bid * 256 + threadIdx.x;
    float4 v = ((const float4*)x)[i];
    ushort4 o;
    o.x = f2b(v.x); o.y = f2b(v.y); o.z = f2b(v.z); o.w = f2b(v.w);
    ((ushort4*)xb)[i] = o;
  } else {                                // Wqkv [768 x 2304] -> [2304 x 768]
    int tb = bid - 3072;
    tr_body(Wqkv, Wqkv_t, CC, 3 * CC, tb % 72, tb / 72, tile);
  }
}

// ============ GEMM core A: 128x96 tile, BK=64, XOR-swizzled LDS, 4 waves ============
// LDS rows = 64 u16 (one bank wrap). Logical chunk c of row r lives at physical
// c^(r&7) (staged via per-lane global source). Frag reads: 2 lanes/bank-run.
// Double-buffered (u16 units): As0 [0,8192) Bs0 [8192,14336)
//                              As1 [14336,22528) Bs1 [22528,28672).
// STAGE7: A = 4 issues (128 rows), B = 3 issues (96 rows) -> vmcnt(7).

#define STAGE7(k0_, Ad_, Bd_)                                                     \
  _Pragma("unroll") for (int i_ = 0; i_ < 4; i_++)                                \
    gload_lds16(ga + i_ * 32 * CC + (k0_), (Ad_) + i_ * 2048 + tid * 8);          \
  _Pragma("unroll") for (int i_ = 0; i_ < 3; i_++)                                \
    gload_lds16(gb + i_ * 32 * CC + (k0_), (Bd_) + i_ * 2048 + tid * 8);

#define COMPUTE96(As_, Bs_)                                                       \
  { bf16x8 af[4][2], bfr[3][2];                                                   \
    _Pragma("unroll") for (int i = 0; i < 4; i++) {                               \
      const u16* ar = (As_) + (wm + i * 16 + id16) * 64;                          \
      af[i][0] = *(const bf16x8*)(ar + off0);                                     \
      af[i][1] = *(const bf16x8*)(ar + off1);                                     \
    }                                                                             \
    _Pragma("unroll") for (int j = 0; j < 3; j++) {                               \
      const u16* br = (Bs_) + (wn48 + j * 16 + id16) * 64;                        \
      bfr[j][0] = *(const bf16x8*)(br + off0);                                    \
      bfr[j][1] = *(const bf16x8*)(br + off1);                                    \
    }                                                                             \
    _Pragma("unroll") for (int i = 0; i < 4; i++)                                 \
      _Pragma("unroll") for (int j = 0; j < 3; j++) {                             \
        acc[i][j] = __builtin_amdgcn_mfma_f32_16x16x32_bf16(af[i][0], bfr[j][0],  \
                                                            acc[i][j], 0, 0, 0);  \
        acc[i][j] = __builtin_amdgcn_mfma_f32_16x16x32_bf16(af[i][1], bfr[j][1],  \
                                                            acc[i][j], 0, 0, 0);  \
      } }

// fences: s_waitcnt vmcnt(N) as asm-with-memory-clobber orders all memory ops
// around it; empty asm after each raw barrier stops ds_reads/gload_lds from
// being compiler-hoisted across the rendezvous.
#define GEMM_CORE96_DB(A_, Bt_, m0_, n0_, SMEM)                                   \
  u16* As0 = (SMEM);          u16* Bs0 = (SMEM) + 8192;                           \
  u16* As1 = (SMEM) + 14336;  u16* Bs1 = (SMEM) + 22528;                          \
  int tid = threadIdx.x;                                                          \
  int wave = tid >> 6, lane = tid & 63, quad = lane >> 4, id16 = lane & 15;       \
  int wm = (wave & 1) * 64, wn48 = (wave >> 1) * 48;                              \
  int srow = tid >> 3;                                                            \
  int schunk = (tid & 7) ^ (srow & 7);                                            \
  const u16* ga = A_ + (m0_ + srow) * CC + schunk * 8;                            \
  const u16* gb = Bt_ + (n0_ + srow) * CC + schunk * 8;                           \
  int xk = id16 & 7;                                                              \
  int off0 = (quad ^ xk) * 8, off1 = ((4 + quad) ^ xk) * 8;                       \
  f32x4 acc[4][3];                                                                \
  _Pragma("unroll") for (int i = 0; i < 4; i++)                                   \
      _Pragma("unroll") for (int j = 0; j < 3; j++) acc[i][j] = (f32x4){0,0,0,0}; \
  STAGE7(0, As0, Bs0)                                                             \
  for (int kk = 0; kk < 6; kk++) {                                                \
    int kA = kk * 128;                                                            \
    /* phase A: prefetch buf1@kA+64, compute buf0@kA */                           \
    STAGE7(kA + 64, As1, Bs1)                                                     \
    asm volatile("s_waitcnt vmcnt(7)" ::: "memory");                              \
    __builtin_amdgcn_s_barrier();                                                 \
    asm volatile("" ::: "memory");                                                \
    COMPUTE96(As0, Bs0)                                                           \
    __builtin_amdgcn_s_barrier();                                                 \
    asm volatile("" ::: "memory");                                                \
    /* phase B: prefetch buf0@kA+128 (unless last), compute buf1@kA+64 */         \
    if (kk < 5) {                                                                 \
      STAGE7(kA + 128, As0, Bs0)                                                  \
      asm volatile("s_waitcnt vmcnt(7)" ::: "memory");                            \
    } else {                                                                      \
      asm volatile("s_waitcnt vmcnt(0)" ::: "memory");                            \
    }                                                                             \
    __builtin_amdgcn_s_barrier();                                                 \
    asm volatile("" ::: "memory");                                                \
    COMPUTE96(As1, Bs1)                                                           \
    __builtin_amdgcn_s_barrier();                                                 \
    asm volatile("" ::: "memory");                                                \
  }

// ============ GEMM core B: 64x96 tile, BK=64 (k_proj; 2 blocks/CU) ============
// LDS (u16): As 4096, Bs 6144 per buf. As0[0,4096) Bs0[4096,10240)
//            As1[10240,14336) Bs1[14336,20480). Total 40KB.
// STAGE5: A = 2 issues (64 rows), B = 3 issues (96 rows) -> vmcnt(5).
#define STAGE5(k0_, Ad_, Bd_)                                                     \
  _Pragma("unroll") for (int i_ = 0; i_ < 2; i_++)                                \
    gload_lds16(ga + i_ * 32 * CC + (k0_), (Ad_) + i_ * 2048 + tid * 8);          \
  _Pragma("unroll") for (int i_ = 0; i_ < 3; i_++)                                \
    gload_lds16(gb + i_ * 32 * CC + (k0_), (Bd_) + i_ * 2048 + tid * 8);

#define COMPUTE6496(As_, Bs_)                                                     \
  { bf16x8 af[2][2], bfr[3][2];                                                   \
    _Pragma("unroll") for (int i = 0; i < 2; i++) {                               \
      const u16* ar = (As_) + (wm32 + i * 16 + id16) * 64;                        \
      af[i][0] = *(const bf16x8*)(ar + off0);                                     \
      af[i][1] = *(const bf16x8*)(ar + off1);                                     \
    }                                                                             \
    _Pragma("unroll") for (int j = 0; j < 3; j++) {                               \
      const u16* br = (Bs_) + (wn48 + j * 16 + id16) * 64;                        \
      bfr[j][0] = *(const bf16x8*)(br + off0);                                    \
      bfr[j][1] = *(const bf16x8*)(br + off1);                                    \
    }                                                                             \
    _Pragma("unroll") for (int i = 0; i < 2; i++)                                 \
      _Pragma("unroll") for (int j = 0; j < 3; j++) {                             \
        acc[i][j] = __builtin_amdgcn_mfma_f32_16x16x32_bf16(af[i][0], bfr[j][0],  \
                                                            acc[i][j], 0, 0, 0);  \
        acc[i][j] = __builtin_amdgcn_mfma_f32_16x16x32_bf16(af[i][1], bfr[j][1],  \
                                                            acc[i][j], 0, 0, 0);  \
      } }

#define GEMM_CORE6496_DB(A_, Bt_, m0_, n0_, SMEM)                                 \
  u16* As0 = (SMEM);          u16* Bs0 = (SMEM) + 4096;                           \
  u16* As1 = (SMEM) + 10240;  u16* Bs1 = (SMEM) + 14336;                          \
  int tid = threadIdx.x;                                                          \
  int wave = tid >> 6, lane = tid & 63, quad = lane >> 4, id16 = lane & 15;       \
  int wm32 = (wave & 1) * 32, wn48 = (wave >> 1) * 48;                            \
  int srow = tid >> 3;                                                            \
  int schunk = (tid & 7) ^ (srow & 7);                                            \
  const u16* ga = A_ + (m0_ + srow) * CC + schunk * 8;                            \
  const u16* gb = Bt_ + (n0_ + srow) * CC + schunk * 8;                           \
  int xk = id16 & 7;                                                              \
  int off0 = (quad ^ xk) * 8, off1 = ((4 + quad) ^ xk) * 8;                       \
  f32x4 acc[2][3];                                                                \
  _Pragma("unroll") for (int i = 0; i < 2; i++)                                   \
      _Pragma("unroll") for (int j = 0; j < 3; j++) acc[i][j] = (f32x4){0,0,0,0}; \
  STAGE5(0, As0, Bs0)                                                             \
  for (int kk = 0; kk < 6; kk++) {                                                \
    int kA = kk * 128;                                                            \
    STAGE5(kA + 64, As1, Bs1)                                                     \
    asm volatile("s_waitcnt vmcnt(5)" ::: "memory");                              \
    __builtin_amdgcn_s_barrier();                                                 \
    asm volatile("" ::: "memory");                                                \
    COMPUTE6496(As0, Bs0)                                                         \
    __builtin_amdgcn_s_barrier();                                                 \
    asm volatile("" ::: "memory");                                                \
    if (kk < 5) {                                                                 \
      STAGE5(kA + 128, As0, Bs0)                                                  \
      asm volatile("s_waitcnt vmcnt(5)" ::: "memory");                            \
    } else {                                                                      \
      asm volatile("s_waitcnt vmcnt(0)" ::: "memory");                            \
    }                                                                             \
    __builtin_amdgcn_s_barrier();                                                 \
    asm volatile("" ::: "memory");                                                \
    COMPUTE6496(As1, Bs1)                                                         \
    __builtin_amdgcn_s_barrier();                                                 \
    asm volatile("" ::: "memory");                                                \
  }

// ---------- QKV GEMM: xb[4096x768] @ Wqkv_t^T + bias -> Qb/Kb/Vt ----------
// 768 blocks = 32 m-groups x 24 n-tiles (3.00/CU). 768 = 8 XCD x 96.
__global__ __launch_bounds__(256) void k_qkv(const u16* __restrict__ A, const u16* __restrict__ Bt,
                                             const float* __restrict__ bias,
                                             u16* __restrict__ Qb, u16* __restrict__ Kb,
                                             u16* __restrict__ Vt) {
  __shared__ u16 smem[28672];   // GEMM dbuf 57.3KB; epilogue reuses [0,13312)
  int xcd = blockIdx.x & 7, g = blockIdx.x >> 3;            // g in [0,96)
  int m0 = (xcd + 8 * (g / 24)) * 128, n0 = (g % 24) * 96;  // same-m0 -> same XCD
  GEMM_CORE96_DB(A, Bt, m0, n0, smem)
  float bv[3];
#pragma unroll
  for (int j = 0; j < 3; j++) bv[j] = bias[n0 + wn48 + j * 16 + id16];
  int bi = m0 >> 10, t0 = m0 & 1023;

  if (n0 < 2 * CC) {
    // Q or K tile: stage [128 m][96 n] rows in smem (stride 104), then copy
    // per 32-col unit (never crosses a 64-col head boundary: n0%64 in {0,32}).
    u16* dstb = (n0 < CC) ? Qb : Kb;
    int nrel0 = (n0 < CC) ? n0 : n0 - CC;
#pragma unroll
    for (int i = 0; i < 4; i++)
#pragma unroll
      for (int j = 0; j < 3; j++)
#pragma unroll
        for (int r = 0; r < 4; r++)
          smem[(wm + i * 16 + quad * 4 + r) * 104 + wn48 + j * 16 + id16] =
              f2b(acc[i][j][r] + bv[j]);
    __syncthreads();
#pragma unroll
    for (int u = tid; u < 384; u += 256) {      // 128 rows x 3 segs of 32 cols
      int row = u / 3, seg = u % 3;
      int ng = nrel0 + seg * 32;
      int h = ng >> 6, d0 = ng & 63;
      const u16* src = smem + row * 104 + seg * 32;
      u16* dst = dstb + ((bi * NHH + h) * TT + t0 + row) * HDD + d0;
#pragma unroll
      for (int w2 = 0; w2 < 4; w2++)
        ((bf16x8*)dst)[w2] = ((const bf16x8*)src)[w2];
    }
  } else {
    // V tile: stage transposed [96 n][128 m] (stride 136), copy 64-u16 halves.
#pragma unroll
    for (int i = 0; i < 4; i++)
#pragma unroll
      for (int j = 0; j < 3; j++)
#pragma unroll
        for (int r = 0; r < 4; r++)
          smem[(wn48 + j * 16 + id16) * 136 + wm + i * 16 + quad * 4 + r] =
              f2b(acc[i][j][r] + bv[j]);
    __syncthreads();
    if (tid < 192) {                            // 96 rows x 2 m-segs
      int row = tid >> 1, mseg = tid & 1;
      int dd = n0 - 2 * CC + row;
      int h = dd >> 6, d = dd & 63;
      const u16* src = smem + row * 136 + mseg * 64;
      u16* dst = Vt + ((bi * NHH + h) * HDD + d) * TT + t0 + mseg * 64;
#pragma unroll
      for (int w2 = 0; w2 < 8; w2++)
        ((bf16x8*)dst)[w2] = ((const bf16x8*)src)[w2];
    }
  }
}

// ---------- Proj GEMM: Ob[4096x768] @ Wproj_t^T + bias -> out fp32 ----------
// 512 blocks = 64 m-tiles x 8 n-tiles (2.00/CU even, 2 waves/SIMD).
__global__ __launch_bounds__(256) void k_proj(const u16* __restrict__ A, const u16* __restrict__ Bt,
                                              const float* __restrict__ bias, float* __restrict__ out) {
  __shared__ u16 smem[20480];
  int xcd = blockIdx.x & 7, g = blockIdx.x >> 3;           // g in [0,64)
  int m0 = (xcd + 8 * (g / 8)) * 64, n0 = (g % 8) * 96;    // same-m0 -> same XCD
  GEMM_CORE6496_DB(A, Bt, m0, n0, smem)
  float bv[3];
#pragma unroll
  for (int j = 0; j < 3; j++) bv[j] = bias[n0 + wn48 + j * 16 + id16];
#pragma unroll
  for (int i = 0; i < 2; i++) {
#pragma unroll
    for (int j = 0; j < 3; j++) {
#pragma unroll
      for (int r = 0; r < 4; r++) {
        int m = m0 + wm32 + i * 16 + quad * 4 + r;
        int n = n0 + wn48 + j * 16 + id16;
        out[m * CC + n] = acc[i][j][r] + bv[j];
      }
    }
  }
}

// ---------- Flash attention: 2 waves x 64 q-rows, staged, + Wproj-tail ----------
// grid = 384 attn blocks (block = 128 q rows; wave w owns rows [qw, qw+64))
// + 576 appended blocks doing the Wproj transpose. Heavy-first. Per chunk the
// K/V frags are loaded once and reused by 4 rh-subtiles (2x MFMA per ds_read
// vs R21). Wave 0 skips its one above-diag chunk (wave-uniform continue;
// prefetch issued before the skip, so barrier & stage counts stay uniform).
__global__ __launch_bounds__(128) void k_attn(const u16* __restrict__ Qb, const u16* __restrict__ Kb,
                                              const u16* __restrict__ Vt, u16* __restrict__ Ob,
                                              const float* __restrict__ Wproj,
                                              u16* __restrict__ Wproj_t) {
  __shared__ __align__(16) u16 Ks[2][64 * 64];    // [buf][key][d-chunks swizzled]
  __shared__ __align__(16) u16 Vs[2][64 * 64];    // [buf][d][key-chunks swizzled]
  int tid = threadIdx.x;

  if (blockIdx.x >= 8 * BHH) {
    // Wproj transpose tile (32x32), 128 threads = 32x4, LDS overlaid on Ks.
    float (*tile)[33] = (float (*)[33])Ks;
    int tb = blockIdx.x - 8 * BHH;               // 0..575
    int c0 = (tb % 24) * 32, r0 = (tb / 24) * 32;
    int tx = tid & 31, ty = tid >> 5;            // 32 x 4
#pragma unroll
    for (int i = 0; i < 32; i += 4)
      tile[ty + i][tx] = Wproj[(r0 + ty + i) * CC + c0 + tx];
    __syncthreads();
#pragma unroll
    for (int i = 0; i < 32; i += 4)
      Wproj_t[(c0 + ty + i) * CC + r0 + tx] = f2b(tile[tx][ty + i]);
    return;
  }

  int wave = tid >> 6, lane = tid & 63, quad = lane >> 4, id16 = lane & 15;
  int bh = blockIdx.x % BHH, t = 7 - (blockIdx.x / BHH);   // 128-row tile idx
  int b = bh / NHH, h = bh % NHH;
  int qw = t * 128 + wave * 64;     // this wave's first q row (64 rows)
  int nch = 2 * t + 2;              // 64-key chunks this block stages
  int mych = 2 * t + 1 + wave;      // chunks this wave computes
  const float cexp = 0.125f * 1.44269504088896f;  // scale * log2(e)
  bf16x8 bones;                     // all-ones A-frag (perm-invariant l)
#pragma unroll
  for (int e = 0; e < 8; e++) bones[e] = (short)0x3F80;

  const u16* Kg = Kb + (bh * TT) * HDD;        // [T][64]
  const u16* Vg = Vt + (bh * HDD) * TT;        // [64][T]
  int srow = tid >> 3;                         // staging row within 16-group
  int schunk = (tid & 7) ^ (srow & 7);         // swizzled source chunk

  // per-lane reader offsets (u16 units), XOR-swizzled by row&7 == id16&7
  int xk = id16 & 7;
  int koff0 = (quad ^ xk) * 8;
  int koff1 = ((quad + 4) ^ xk) * 8;
  int half = (quad & 1) * 4;
  int voff0 = (((quad >> 1)) ^ xk) * 8 + half;
  int voff1 = (((quad >> 1) + 2) ^ xk) * 8 + half;
  int voff2 = (((quad >> 1) + 4) ^ xk) * 8 + half;
  int voff3 = (((quad >> 1) + 6) ^ xk) * 8 + half;

  bf16x8 aq[4][2];                  // 4 x 16 Q rows; B-operand of S^T
#pragma unroll
  for (int rh = 0; rh < 4; rh++) {
    const u16* Qrow = Qb + (bh * TT + qw + 16 * rh + id16) * HDD;
    aq[rh][0] = *(const bf16x8*)(Qrow + quad * 8);
    aq[rh][1] = *(const bf16x8*)(Qrow + 32 + quad * 8);
  }
  f32x4 o[4][4], ol[4];
#pragma unroll
  for (int rh = 0; rh < 4; rh++) {
    ol[rh] = (f32x4){0,0,0,0};
#pragma unroll
    for (int dt = 0; dt < 4; dt++) o[rh][dt] = (f32x4){0,0,0,0};
  }

  // stage chunk 0 into buf 0 (swizzled source chunk -> physical chunk tid&7)
#pragma unroll
  for (int i = 0; i < 4; i++) {
    gload_lds16(Kg + (16 * i + srow) * HDD + schunk * 8, Ks[0] + i * 1024 + tid * 8);
    gload_lds16(Vg + (16 * i + srow) * TT + schunk * 8, Vs[0] + i * 1024 + tid * 8);
  }

  for (int c = 0; c < nch; c++) {
    __syncthreads();
    if (c + 1 < nch) {
      int kb = (c + 1) * 64;
      u16* kd = Ks[(c + 1) & 1];
      u16* vd = Vs[(c + 1) & 1];
#pragma unroll
      for (int i = 0; i < 4; i++) {
        gload_lds16(Kg + (kb + 16 * i + srow) * HDD + schunk * 8, kd + i * 1024 + tid * 8);
        gload_lds16(Vg + (16 * i + srow) * TT + kb + schunk * 8, vd + i * 1024 + tid * 8);
      }
    }
    if (c >= mych) continue;        // wave-uniform; next iter starts at barrier
    const u16* kbuf = Ks[c & 1];
    const u16* vbuf = Vs[c & 1];
    bool diag = (c == mych - 1);
    int kb = c * 64;

    // K frags (A-op of S^T), swizzled chunks: shared by all 4 rh
    bf16x8 kf0[4], kf1[4];
#pragma unroll
    for (int kt = 0; kt < 4; kt++) {
      const u16* kr = kbuf + (kt * 16 + id16) * 64;
      kf0[kt] = *(const bf16x8*)(kr + koff0);
      kf1[kt] = *(const bf16x8*)(kr + koff1);
    }
    // V frags (A-op of O^T), key-permuted + swizzled: uint2 pair assembly
    bf16x8 vf0[4], vf1[4];
#pragma unroll
    for (int dt = 0; dt < 4; dt++) {
      const u16* vr = vbuf + (dt * 16 + id16) * 64;
      uint2 a0 = *(const uint2*)(vr + voff0);
      uint2 a1 = *(const uint2*)(vr + voff1);
      uint2 a2 = *(const uint2*)(vr + voff2);
      uint2 a3 = *(const uint2*)(vr + voff3);
      i32x4 w0, w1;
      w0.x = a0.x; w0.y = a0.y; w0.z = a1.x; w0.w = a1.y;
      w1.x = a2.x; w1.y = a2.y; w1.z = a3.x; w1.w = a3.y;
      vf0[dt] = __builtin_bit_cast(bf16x8, w0);
      vf1[dt] = __builtin_bit_cast(bf16x8, w1);
    }

#pragma unroll
    for (int rh = 0; rh < 4; rh++) {
      // S^T [64 keys x 16 q]: lane reg (kt,r) = key kb+kt*16+quad*4+r, q = id16
      f32x4 st[4];
#pragma unroll
      for (int kt = 0; kt < 4; kt++) {
        f32x4 z = {0,0,0,0};
        z = __builtin_amdgcn_mfma_f32_16x16x32_bf16(kf0[kt], aq[rh][0], z, 0, 0, 0);
        st[kt] = __builtin_amdgcn_mfma_f32_16x16x32_bf16(kf1[kt], aq[rh][1], z, 0, 0, 0);
      }
      // exp2 (+ mask on diag chunk), pack r-pairs into dwords IN-LANE
      unsigned pk[4][2];
      if (!diag) {
#pragma unroll
        for (int kt = 0; kt < 4; kt++) {
          pk[kt][0] = packbf(__builtin_amdgcn_exp2f(st[kt][0] * cexp),
                             __builtin_amdgcn_exp2f(st[kt][1] * cexp));
          pk[kt][1] = packbf(__builtin_amdgcn_exp2f(st[kt][2] * cexp),
                             __builtin_amdgcn_exp2f(st[kt][3] * cexp));
        }
      } else {
        int qrow = qw + 16 * rh + id16;
#pragma unroll
        for (int kt = 0; kt < 4; kt++) {
          float pv[4];
#pragma unroll
          for (int r = 0; r < 4; r++) {
            int key = kb + kt * 16 + quad * 4 + r;
            float p = __builtin_amdgcn_exp2f(st[kt][r] * cexp);
            pv[r] = (key <= qrow) ? p : 0.f;
          }
          pk[kt][0] = packbf(pv[0], pv[1]);
          pk[kt][1] = packbf(pv[2], pv[3]);
        }
      }
      // P^T B-operand frags = pk registers directly (key-permuted PV)
      i32x4 b0v, b1v;
      b0v.x = (int)pk[0][0]; b0v.y = (int)pk[0][1];
      b0v.z = (int)pk[1][0]; b0v.w = (int)pk[1][1];
      b1v.x = (int)pk[2][0]; b1v.y = (int)pk[2][1];
      b1v.z = (int)pk[3][0]; b1v.w = (int)pk[3][1];
      bf16x8 pf0 = __builtin_bit_cast(bf16x8, b0v);
      bf16x8 pf1 = __builtin_bit_cast(bf16x8, b1v);

      // O^T += V^T * P^T  (A = vf frags); l via all-ones A-frag
#pragma unroll
      for (int dt = 0; dt < 4; dt++) {
        o[rh][dt] = __builtin_amdgcn_mfma_f32_16x16x32_bf16(vf0[dt], pf0, o[rh][dt], 0, 0, 0);
        o[rh][dt] = __builtin_amdgcn_mfma_f32_16x16x32_bf16(vf1[dt], pf1, o[rh][dt], 0, 0, 0);
      }
      ol[rh] = __builtin_amdgcn_mfma_f32_16x16x32_bf16(bones, pf0, ol[rh], 0, 0, 0);
      ol[rh] = __builtin_amdgcn_mfma_f32_16x16x32_bf16(bones, pf1, ol[rh], 0, 0, 0);
    }
  }

  // epilogue: lane holds O^T[d = dt*16+quad*4+r][q = qw+16rh+id16]; l = ol[rh][0]
#pragma unroll
  for (int rh = 0; rh < 4; rh++) {
    float inv = 1.0f / ol[rh][0];
    int qg = qw + 16 * rh + id16;
    u16* dst = Ob + (b * TT + qg) * CC + h * HDD + quad * 4;
#pragma unroll
    for (int dt = 0; dt < 4; dt++) {
      unsigned lo = ((unsigned)f2b(o[rh][dt][1] * inv) << 16) | f2b(o[rh][dt][0] * inv);
      unsigned hi = ((unsigned)f2b(o[rh][dt][3] * inv) << 16) | f2b(o[rh][dt][2] * inv);
      uint2 pairv; pairv.x = lo; pairv.y = hi;
      *(uint2*)(dst + dt * 16) = pairv;
    }
  }
}

extern "C" void kernel_launch(void* const* d_in, const int* in_sizes, int n_in,
                              void* d_out, int out_size, void* d_ws, size_t ws_size,
                              hipStream_t stream) {
  const float* x     = (const float*)d_in[0];
  const float* Wqkv  = (const float*)d_in[1];
  const float* bqkv  = (const float*)d_in[2];
  const float* Wproj = (const float*)d_in[3];
  const float* bproj = (const float*)d_in[4];
  // d_in[5] = start_pos (always 0; KV-cache write+slice is identity)
  float* out = (float*)d_out;

  u16* ws = (u16*)d_ws;
  u16* xb      = ws;                              // [4096 x 768]
  u16* Wqkv_t  = xb + BB * TT * CC;               // [2304 x 768]
  u16* Wproj_t = Wqkv_t + 3 * CC * CC;            // [768 x 768]
  u16* Qb      = Wproj_t + CC * CC;               // [BH][T][64]
  u16* Kb      = Qb + BHH * TT * HDD;             // [BH][T][64]
  u16* Vt      = Kb + BHH * TT * HDD;             // [BH][64][T]
  u16* Ob      = Vt + BHH * TT * HDD;             // [4096 x 768]

  k_prep<<<3072 + 1728, 256, 0, stream>>>(x, xb, Wqkv, Wqkv_t);
  k_qkv<<<32 * 24, 256, 0, stream>>>(xb, Wqkv_t, bqkv, Qb, Kb, Vt);
  k_attn<<<8 * BHH + 576, 128, 0, stream>>>(Qb, Kb, Vt, Ob, Wproj, Wproj_t);
  k_proj<<<64 * 8, 256, 0, stream>>>(Ob, Wproj_t, bproj, out);
}

// Round 10
// 130.782 us; speedup vs baseline: 1.0652x; 1.0652x over previous
//
#include <hip/hip_runtime.h>

// CausalSelfAttention: B=4 T=1024 C=768 NH=12 HD=64, start_pos=0.
// Round 24: REVERT R23 (64x96 k_qkv rewrite failed correctness; bug not
//   localizable by inspection -> revert per rigor discipline). This is the
//   R21 kernel verbatim = best passing config (131.2 us).
// Round 21: k_proj 64x96, 512 blocks 2.00/CU (2 waves/SIMD).
// Round 20: Wproj transpose fused into k_attn tail blocks.
// Round 18: k_qkv 128x96, 768 blocks 3.00/CU; N=96 grid quantization.
// Round 15: GEMM 2-deep LDS dbuf + counted s_waitcnt vmcnt(N).
// MFMA 16x16x32 bf16 layouts (HW-verified per guide):
//   A-op:  A[m=lane&15][k=(lane>>4)*8+j]   (8 bf16 / lane, contiguous in k)
//   B-op:  B[k=(lane>>4)*8+j][n=lane&15]   (contiguous in k)
//   C/D :  C[row=(lane>>4)*4+reg][col=lane&15]

#define BB 4
#define TT 1024
#define CC 768
#define NHH 12
#define HDD 64
#define BHH (BB*NHH)

typedef unsigned short u16;
typedef __attribute__((ext_vector_type(8))) short bf16x8;
typedef __attribute__((ext_vector_type(4))) float f32x4;
typedef __attribute__((ext_vector_type(4))) int i32x4;

__device__ __forceinline__ u16 f2b(float f) {
  unsigned u = __float_as_uint(f);
  u += 0x7fffu + ((u >> 16) & 1u);   // RTNE
  return (u16)(u >> 16);
}
// pack two floats' high halves into one dword (truncating bf16; P in [0,1])
__device__ __forceinline__ unsigned packbf(float lo, float hi) {
  return (__float_as_uint(hi) & 0xffff0000u) | (__float_as_uint(lo) >> 16);
}

// async global->LDS, 16B per lane; LDS dest must be wave-uniform base + lane*16
__device__ __forceinline__ void gload_lds16(const u16* g, u16* l) {
  __builtin_amdgcn_global_load_lds(
      (const __attribute__((address_space(1))) unsigned int*)g,
      (__attribute__((address_space(3))) unsigned int*)l, 16, 0, 0);
}

// ---------- prep: x fp32->bf16 cvt  +  Wqkv transpose (Wproj in k_attn) ----------
__device__ __forceinline__ void tr_body(const float* __restrict__ in, u16* __restrict__ out,
                                        int R, int Cc, int bx, int by, float (*tile)[33]) {
  int c0 = bx * 32, r0 = by * 32;
  int tx = threadIdx.x & 31, ty = threadIdx.x >> 5;  // 32 x 8
#pragma unroll
  for (int i = 0; i < 32; i += 8)
    tile[ty + i][tx] = in[(r0 + ty + i) * Cc + c0 + tx];
  __syncthreads();
#pragma unroll
  for (int i = 0; i < 32; i += 8)
    out[(c0 + ty + i) * R + r0 + tx] = f2b(tile[tx][ty + i]);
}

__global__ __launch_bounds__(256) void k_prep(const float* __restrict__ x, u16* __restrict__ xb,
                                              const float* __restrict__ Wqkv, u16* __restrict__ Wqkv_t) {
  __shared__ float tile[32][33];
  int bid = blockIdx.x;
  if (bid < 3072) {                       // cvt: 786432 float4 groups
    int i = bid * 256 + threadIdx.x;
    float4 v = ((const float4*)x)[i];
    ushort4 o;
    o.x = f2b(v.x); o.y = f2b(v.y); o.z = f2b(v.z); o.w = f2b(v.w);
    ((ushort4*)xb)[i] = o;
  } else {                                // Wqkv [768 x 2304] -> [2304 x 768]
    int tb = bid - 3072;
    tr_body(Wqkv, Wqkv_t, CC, 3 * CC, tb % 72, tb / 72, tile);
  }
}

// ============ GEMM core A: 128x96 tile, BK=64, XOR-swizzled LDS, 4 waves ============
// LDS rows = 64 u16 (one bank wrap). Logical chunk c of row r lives at physical
// c^(r&7) (staged via per-lane global source). Frag reads: 2 lanes/bank-run.
// Double-buffered (u16 units): As0 [0,8192) Bs0 [8192,14336)
//                              As1 [14336,22528) Bs1 [22528,28672).
// STAGE7: A = 4 issues (128 rows), B = 3 issues (96 rows) -> vmcnt(7).

#define STAGE7(k0_, Ad_, Bd_)                                                     \
  _Pragma("unroll") for (int i_ = 0; i_ < 4; i_++)                                \
    gload_lds16(ga + i_ * 32 * CC + (k0_), (Ad_) + i_ * 2048 + tid * 8);          \
  _Pragma("unroll") for (int i_ = 0; i_ < 3; i_++)                                \
    gload_lds16(gb + i_ * 32 * CC + (k0_), (Bd_) + i_ * 2048 + tid * 8);

#define COMPUTE96(As_, Bs_)                                                       \
  { bf16x8 af[4][2], bfr[3][2];                                                   \
    _Pragma("unroll") for (int i = 0; i < 4; i++) {                               \
      const u16* ar = (As_) + (wm + i * 16 + id16) * 64;                          \
      af[i][0] = *(const bf16x8*)(ar + off0);                                     \
      af[i][1] = *(const bf16x8*)(ar + off1);                                     \
    }                                                                             \
    _Pragma("unroll") for (int j = 0; j < 3; j++) {                               \
      const u16* br = (Bs_) + (wn48 + j * 16 + id16) * 64;                        \
      bfr[j][0] = *(const bf16x8*)(br + off0);                                    \
      bfr[j][1] = *(const bf16x8*)(br + off1);                                    \
    }                                                                             \
    _Pragma("unroll") for (int i = 0; i < 4; i++)                                 \
      _Pragma("unroll") for (int j = 0; j < 3; j++) {                             \
        acc[i][j] = __builtin_amdgcn_mfma_f32_16x16x32_bf16(af[i][0], bfr[j][0],  \
                                                            acc[i][j], 0, 0, 0);  \
        acc[i][j] = __builtin_amdgcn_mfma_f32_16x16x32_bf16(af[i][1], bfr[j][1],  \
                                                            acc[i][j], 0, 0, 0);  \
      } }

// fences: s_waitcnt vmcnt(N) as asm-with-memory-clobber orders all memory ops
// around it; empty asm after each raw barrier stops ds_reads/gload_lds from
// being compiler-hoisted across the rendezvous.
#define GEMM_CORE96_DB(A_, Bt_, m0_, n0_, SMEM)                                   \
  u16* As0 = (SMEM);          u16* Bs0 = (SMEM) + 8192;                           \
  u16* As1 = (SMEM) + 14336;  u16* Bs1 = (SMEM) + 22528;                          \
  int tid = threadIdx.x;                                                          \
  int wave = tid >> 6, lane = tid & 63, quad = lane >> 4, id16 = lane & 15;       \
  int wm = (wave & 1) * 64, wn48 = (wave >> 1) * 48;                              \
  int srow = tid >> 3;                                                            \
  int schunk = (tid & 7) ^ (srow & 7);                                            \
  const u16* ga = A_ + (m0_ + srow) * CC + schunk * 8;                            \
  const u16* gb = Bt_ + (n0_ + srow) * CC + schunk * 8;                           \
  int xk = id16 & 7;                                                              \
  int off0 = (quad ^ xk) * 8, off1 = ((4 + quad) ^ xk) * 8;                       \
  f32x4 acc[4][3];                                                                \
  _Pragma("unroll") for (int i = 0; i < 4; i++)                                   \
      _Pragma("unroll") for (int j = 0; j < 3; j++) acc[i][j] = (f32x4){0,0,0,0}; \
  STAGE7(0, As0, Bs0)                                                             \
  for (int kk = 0; kk < 6; kk++) {                                                \
    int kA = kk * 128;                                                            \
    /* phase A: prefetch buf1@kA+64, compute buf0@kA */                           \
    STAGE7(kA + 64, As1, Bs1)                                                     \
    asm volatile("s_waitcnt vmcnt(7)" ::: "memory");                              \
    __builtin_amdgcn_s_barrier();                                                 \
    asm volatile("" ::: "memory");                                                \
    COMPUTE96(As0, Bs0)                                                           \
    __builtin_amdgcn_s_barrier();                                                 \
    asm volatile("" ::: "memory");                                                \
    /* phase B: prefetch buf0@kA+128 (unless last), compute buf1@kA+64 */         \
    if (kk < 5) {                                                                 \
      STAGE7(kA + 128, As0, Bs0)                                                  \
      asm volatile("s_waitcnt vmcnt(7)" ::: "memory");                            \
    } else {                                                                      \
      asm volatile("s_waitcnt vmcnt(0)" ::: "memory");                            \
    }                                                                             \
    __builtin_amdgcn_s_barrier();                                                 \
    asm volatile("" ::: "memory");                                                \
    COMPUTE96(As1, Bs1)                                                           \
    __builtin_amdgcn_s_barrier();                                                 \
    asm volatile("" ::: "memory");                                                \
  }

// ============ GEMM core B: 64x96 tile, BK=64 (k_proj; 2 blocks/CU) ============
// LDS (u16): As 4096, Bs 6144 per buf. As0[0,4096) Bs0[4096,10240)
//            As1[10240,14336) Bs1[14336,20480). Total 40KB.
// STAGE5: A = 2 issues (64 rows), B = 3 issues (96 rows) -> vmcnt(5).
#define STAGE5(k0_, Ad_, Bd_)                                                     \
  _Pragma("unroll") for (int i_ = 0; i_ < 2; i_++)                                \
    gload_lds16(ga + i_ * 32 * CC + (k0_), (Ad_) + i_ * 2048 + tid * 8);          \
  _Pragma("unroll") for (int i_ = 0; i_ < 3; i_++)                                \
    gload_lds16(gb + i_ * 32 * CC + (k0_), (Bd_) + i_ * 2048 + tid * 8);

#define COMPUTE6496(As_, Bs_)                                                     \
  { bf16x8 af[2][2], bfr[3][2];                                                   \
    _Pragma("unroll") for (int i = 0; i < 2; i++) {                               \
      const u16* ar = (As_) + (wm32 + i * 16 + id16) * 64;                        \
      af[i][0] = *(const bf16x8*)(ar + off0);                                     \
      af[i][1] = *(const bf16x8*)(ar + off1);                                     \
    }                                                                             \
    _Pragma("unroll") for (int j = 0; j < 3; j++) {                               \
      const u16* br = (Bs_) + (wn48 + j * 16 + id16) * 64;                        \
      bfr[j][0] = *(const bf16x8*)(br + off0);                                    \
      bfr[j][1] = *(const bf16x8*)(br + off1);                                    \
    }                                                                             \
    _Pragma("unroll") for (int i = 0; i < 2; i++)                                 \
      _Pragma("unroll") for (int j = 0; j < 3; j++) {                             \
        acc[i][j] = __builtin_amdgcn_mfma_f32_16x16x32_bf16(af[i][0], bfr[j][0],  \
                                                            acc[i][j], 0, 0, 0);  \
        acc[i][j] = __builtin_amdgcn_mfma_f32_16x16x32_bf16(af[i][1], bfr[j][1],  \
                                                            acc[i][j], 0, 0, 0);  \
      } }

#define GEMM_CORE6496_DB(A_, Bt_, m0_, n0_, SMEM)                                 \
  u16* As0 = (SMEM);          u16* Bs0 = (SMEM) + 4096;                           \
  u16* As1 = (SMEM) + 10240;  u16* Bs1 = (SMEM) + 14336;                          \
  int tid = threadIdx.x;                                                          \
  int wave = tid >> 6, lane = tid & 63, quad = lane >> 4, id16 = lane & 15;       \
  int wm32 = (wave & 1) * 32, wn48 = (wave >> 1) * 48;                            \
  int srow = tid >> 3;                                                            \
  int schunk = (tid & 7) ^ (srow & 7);                                            \
  const u16* ga = A_ + (m0_ + srow) * CC + schunk * 8;                            \
  const u16* gb = Bt_ + (n0_ + srow) * CC + schunk * 8;                           \
  int xk = id16 & 7;                                                              \
  int off0 = (quad ^ xk) * 8, off1 = ((4 + quad) ^ xk) * 8;                       \
  f32x4 acc[2][3];                                                                \
  _Pragma("unroll") for (int i = 0; i < 2; i++)                                   \
      _Pragma("unroll") for (int j = 0; j < 3; j++) acc[i][j] = (f32x4){0,0,0,0}; \
  STAGE5(0, As0, Bs0)                                                             \
  for (int kk = 0; kk < 6; kk++) {                                                \
    int kA = kk * 128;                                                            \
    STAGE5(kA + 64, As1, Bs1)                                                     \
    asm volatile("s_waitcnt vmcnt(5)" ::: "memory");                              \
    __builtin_amdgcn_s_barrier();                                                 \
    asm volatile("" ::: "memory");                                                \
    COMPUTE6496(As0, Bs0)                                                         \
    __builtin_amdgcn_s_barrier();                                                 \
    asm volatile("" ::: "memory");                                                \
    if (kk < 5) {                                                                 \
      STAGE5(kA + 128, As0, Bs0)                                                  \
      asm volatile("s_waitcnt vmcnt(5)" ::: "memory");                            \
    } else {                                                                      \
      asm volatile("s_waitcnt vmcnt(0)" ::: "memory");                            \
    }                                                                             \
    __builtin_amdgcn_s_barrier();                                                 \
    asm volatile("" ::: "memory");                                                \
    COMPUTE6496(As1, Bs1)                                                         \
    __builtin_amdgcn_s_barrier();                                                 \
    asm volatile("" ::: "memory");                                                \
  }

// ---------- QKV GEMM: xb[4096x768] @ Wqkv_t^T + bias -> Qb/Kb/Vt ----------
// 768 blocks = 32 m-groups x 24 n-tiles (3.00/CU). 768 = 8 XCD x 96.
__global__ __launch_bounds__(256) void k_qkv(const u16* __restrict__ A, const u16* __restrict__ Bt,
                                             const float* __restrict__ bias,
                                             u16* __restrict__ Qb, u16* __restrict__ Kb,
                                             u16* __restrict__ Vt) {
  __shared__ u16 smem[28672];   // GEMM dbuf 57.3KB; epilogue reuses [0,13312)
  int xcd = blockIdx.x & 7, g = blockIdx.x >> 3;            // g in [0,96)
  int m0 = (xcd + 8 * (g / 24)) * 128, n0 = (g % 24) * 96;  // same-m0 -> same XCD
  GEMM_CORE96_DB(A, Bt, m0, n0, smem)
  float bv[3];
#pragma unroll
  for (int j = 0; j < 3; j++) bv[j] = bias[n0 + wn48 + j * 16 + id16];
  int bi = m0 >> 10, t0 = m0 & 1023;

  if (n0 < 2 * CC) {
    // Q or K tile: stage [128 m][96 n] rows in smem (stride 104), then copy
    // per 32-col unit (never crosses a 64-col head boundary: n0%64 in {0,32}).
    u16* dstb = (n0 < CC) ? Qb : Kb;
    int nrel0 = (n0 < CC) ? n0 : n0 - CC;
#pragma unroll
    for (int i = 0; i < 4; i++)
#pragma unroll
      for (int j = 0; j < 3; j++)
#pragma unroll
        for (int r = 0; r < 4; r++)
          smem[(wm + i * 16 + quad * 4 + r) * 104 + wn48 + j * 16 + id16] =
              f2b(acc[i][j][r] + bv[j]);
    __syncthreads();
#pragma unroll
    for (int u = tid; u < 384; u += 256) {      // 128 rows x 3 segs of 32 cols
      int row = u / 3, seg = u % 3;
      int ng = nrel0 + seg * 32;
      int h = ng >> 6, d0 = ng & 63;
      const u16* src = smem + row * 104 + seg * 32;
      u16* dst = dstb + ((bi * NHH + h) * TT + t0 + row) * HDD + d0;
#pragma unroll
      for (int w2 = 0; w2 < 4; w2++)
        ((bf16x8*)dst)[w2] = ((const bf16x8*)src)[w2];
    }
  } else {
    // V tile: stage transposed [96 n][128 m] (stride 136), copy 64-u16 halves.
#pragma unroll
    for (int i = 0; i < 4; i++)
#pragma unroll
      for (int j = 0; j < 3; j++)
#pragma unroll
        for (int r = 0; r < 4; r++)
          smem[(wn48 + j * 16 + id16) * 136 + wm + i * 16 + quad * 4 + r] =
              f2b(acc[i][j][r] + bv[j]);
    __syncthreads();
    if (tid < 192) {                            // 96 rows x 2 m-segs
      int row = tid >> 1, mseg = tid & 1;
      int dd = n0 - 2 * CC + row;
      int h = dd >> 6, d = dd & 63;
      const u16* src = smem + row * 136 + mseg * 64;
      u16* dst = Vt + ((bi * NHH + h) * HDD + d) * TT + t0 + mseg * 64;
#pragma unroll
      for (int w2 = 0; w2 < 8; w2++)
        ((bf16x8*)dst)[w2] = ((const bf16x8*)src)[w2];
    }
  }
}

// ---------- Proj GEMM: Ob[4096x768] @ Wproj_t^T + bias -> out fp32 ----------
// 512 blocks = 64 m-tiles x 8 n-tiles (2.00/CU even, 2 waves/SIMD).
__global__ __launch_bounds__(256) void k_proj(const u16* __restrict__ A, const u16* __restrict__ Bt,
                                              const float* __restrict__ bias, float* __restrict__ out) {
  __shared__ u16 smem[20480];
  int xcd = blockIdx.x & 7, g = blockIdx.x >> 3;           // g in [0,64)
  int m0 = (xcd + 8 * (g / 8)) * 64, n0 = (g % 8) * 96;    // same-m0 -> same XCD
  GEMM_CORE6496_DB(A, Bt, m0, n0, smem)
  float bv[3];
#pragma unroll
  for (int j = 0; j < 3; j++) bv[j] = bias[n0 + wn48 + j * 16 + id16];
#pragma unroll
  for (int i = 0; i < 2; i++) {
#pragma unroll
    for (int j = 0; j < 3; j++) {
#pragma unroll
      for (int r = 0; r < 4; r++) {
        int m = m0 + wm32 + i * 16 + quad * 4 + r;
        int n = n0 + wn48 + j * 16 + id16;
        out[m * CC + n] = acc[i][j][r] + bv[j];
      }
    }
  }
}

// ---------- Flash attention (staged, R18 structure) + Wproj-transpose tail ----------
// grid = 768 attn blocks (2 waves, 32 q-rows each, heavy-first) + 576 appended
// blocks (idx 768..1343) doing the Wproj [768x768] -> Wproj_t transpose.
__global__ __launch_bounds__(128) void k_attn(const u16* __restrict__ Qb, const u16* __restrict__ Kb,
                                              const u16* __restrict__ Vt, u16* __restrict__ Ob,
                                              const float* __restrict__ Wproj,
                                              u16* __restrict__ Wproj_t) {
  __shared__ __align__(16) u16 Ks[2][64 * 64];    // [buf][key][d-chunks swizzled]
  __shared__ __align__(16) u16 Vs[2][64 * 64];    // [buf][d][key-chunks swizzled]
  int tid = threadIdx.x;

  if (blockIdx.x >= 16 * BHH) {
    // Wproj transpose tile (32x32), 128 threads = 32x4, LDS overlaid on Ks.
    float (*tile)[33] = (float (*)[33])Ks;
    int tb = blockIdx.x - 16 * BHH;              // 0..575
    int c0 = (tb % 24) * 32, r0 = (tb / 24) * 32;
    int tx = tid & 31, ty = tid >> 5;            // 32 x 4
#pragma unroll
    for (int i = 0; i < 32; i += 4)
      tile[ty + i][tx] = Wproj[(r0 + ty + i) * CC + c0 + tx];
    __syncthreads();
#pragma unroll
    for (int i = 0; i < 32; i += 4)
      Wproj_t[(c0 + ty + i) * CC + r0 + tx] = f2b(tile[tx][ty + i]);
    return;
  }

  int wave = tid >> 6, lane = tid & 63, quad = lane >> 4, id16 = lane & 15;
  int bh = blockIdx.x % BHH, t = 15 - (blockIdx.x / BHH);
  int b = bh / NHH, h = bh % NHH;
  int qw = t * 64 + wave * 32;      // this wave's first q row
  int nch = t + 1;                  // 64-key chunks this block runs
  const float cexp = 0.125f * 1.44269504088896f;  // scale * log2(e)
  bf16x8 bones;                     // all-ones A-frag (perm-invariant l)
#pragma unroll
  for (int e = 0; e < 8; e++) bones[e] = (short)0x3F80;

  const u16* Kg = Kb + (bh * TT) * HDD;        // [T][64]
  const u16* Vg = Vt + (bh * HDD) * TT;        // [64][T]
  int srow = tid >> 3;                         // staging row within 16-group
  int schunk = (tid & 7) ^ (srow & 7);         // swizzled source chunk

  // per-lane reader offsets (u16 units), XOR-swizzled by row&7 == id16&7
  int xk = id16 & 7;
  int koff0 = (quad ^ xk) * 8;
  int koff1 = ((quad + 4) ^ xk) * 8;
  int half = (quad & 1) * 4;
  int voff0 = (((quad >> 1)) ^ xk) * 8 + half;
  int voff1 = (((quad >> 1) + 2) ^ xk) * 8 + half;
  int voff2 = (((quad >> 1) + 4) ^ xk) * 8 + half;
  int voff3 = (((quad >> 1) + 6) ^ xk) * 8 + half;

  bf16x8 aq[2][2];                  // Q rows; serve as B-operand of S^T
#pragma unroll
  for (int rh = 0; rh < 2; rh++) {
    const u16* Qrow = Qb + (bh * TT + qw + 16 * rh + id16) * HDD;
    aq[rh][0] = *(const bf16x8*)(Qrow + quad * 8);
    aq[rh][1] = *(const bf16x8*)(Qrow + 32 + quad * 8);
  }
  f32x4 o[2][4], ol[2];
#pragma unroll
  for (int rh = 0; rh < 2; rh++) {
    ol[rh] = (f32x4){0,0,0,0};
#pragma unroll
    for (int dt = 0; dt < 4; dt++) o[rh][dt] = (f32x4){0,0,0,0};
  }

  // stage chunk 0 into buf 0 (swizzled source chunk -> physical chunk tid&7)
#pragma unroll
  for (int i = 0; i < 4; i++) {
    gload_lds16(Kg + (16 * i + srow) * HDD + schunk * 8, Ks[0] + i * 1024 + tid * 8);
    gload_lds16(Vg + (16 * i + srow) * TT + schunk * 8, Vs[0] + i * 1024 + tid * 8);
  }

  for (int c = 0; c < nch; c++) {
    __syncthreads();
    if (c + 1 < nch) {
      int kb = (c + 1) * 64;
      u16* kd = Ks[(c + 1) & 1];
      u16* vd = Vs[(c + 1) & 1];
#pragma unroll
      for (int i = 0; i < 4; i++) {
        gload_lds16(Kg + (kb + 16 * i + srow) * HDD + schunk * 8, kd + i * 1024 + tid * 8);
        gload_lds16(Vg + (16 * i + srow) * TT + kb + schunk * 8, vd + i * 1024 + tid * 8);
      }
    }
    const u16* kbuf = Ks[c & 1];
    const u16* vbuf = Vs[c & 1];
    bool diag = (c == nch - 1);
    int kb = c * 64;

    // K frags (A-op of S^T), swizzled chunks: shared by both rh
    bf16x8 kf0[4], kf1[4];
#pragma unroll
    for (int kt = 0; kt < 4; kt++) {
      const u16* kr = kbuf + (kt * 16 + id16) * 64;
      kf0[kt] = *(const bf16x8*)(kr + koff0);
      kf1[kt] = *(const bf16x8*)(kr + koff1);
    }
    // V frags (A-op of O^T), key-permuted + swizzled: uint2 pair assembly
    bf16x8 vf0[4], vf1[4];
#pragma unroll
    for (int dt = 0; dt < 4; dt++) {
      const u16* vr = vbuf + (dt * 16 + id16) * 64;
      uint2 a0 = *(const uint2*)(vr + voff0);
      uint2 a1 = *(const uint2*)(vr + voff1);
      uint2 a2 = *(const uint2*)(vr + voff2);
      uint2 a3 = *(const uint2*)(vr + voff3);
      i32x4 w0, w1;
      w0.x = a0.x; w0.y = a0.y; w0.z = a1.x; w0.w = a1.y;
      w1.x = a2.x; w1.y = a2.y; w1.z = a3.x; w1.w = a3.y;
      vf0[dt] = __builtin_bit_cast(bf16x8, w0);
      vf1[dt] = __builtin_bit_cast(bf16x8, w1);
    }

#pragma unroll
    for (int rh = 0; rh < 2; rh++) {
      // S^T [64 keys x 16 q]: lane reg (kt,r) = key kb+kt*16+quad*4+r, q = id16
      f32x4 st[4];
#pragma unroll
      for (int kt = 0; kt < 4; kt++) {
        f32x4 z = {0,0,0,0};
        z = __builtin_amdgcn_mfma_f32_16x16x32_bf16(kf0[kt], aq[rh][0], z, 0, 0, 0);
        st[kt] = __builtin_amdgcn_mfma_f32_16x16x32_bf16(kf1[kt], aq[rh][1], z, 0, 0, 0);
      }
      // exp2 (+ mask on diag chunk), pack r-pairs into dwords IN-LANE
      unsigned pk[4][2];
      if (!diag) {
#pragma unroll
        for (int kt = 0; kt < 4; kt++) {
          pk[kt][0] = packbf(__builtin_amdgcn_exp2f(st[kt][0] * cexp),
                             __builtin_amdgcn_exp2f(st[kt][1] * cexp));
          pk[kt][1] = packbf(__builtin_amdgcn_exp2f(st[kt][2] * cexp),
                             __builtin_amdgcn_exp2f(st[kt][3] * cexp));
        }
      } else {
        int qrow = qw + 16 * rh + id16;
#pragma unroll
        for (int kt = 0; kt < 4; kt++) {
          float pv[4];
#pragma unroll
          for (int r = 0; r < 4; r++) {
            int key = kb + kt * 16 + quad * 4 + r;
            float p = __builtin_amdgcn_exp2f(st[kt][r] * cexp);
            pv[r] = (key <= qrow) ? p : 0.f;
          }
          pk[kt][0] = packbf(pv[0], pv[1]);
          pk[kt][1] = packbf(pv[2], pv[3]);
        }
      }
      // P^T B-operand frags = pk registers directly (key-permuted PV)
      i32x4 b0v, b1v;
      b0v.x = (int)pk[0][0]; b0v.y = (int)pk[0][1];
      b0v.z = (int)pk[1][0]; b0v.w = (int)pk[1][1];
      b1v.x = (int)pk[2][0]; b1v.y = (int)pk[2][1];
      b1v.z = (int)pk[3][0]; b1v.w = (int)pk[3][1];
      bf16x8 pf0 = __builtin_bit_cast(bf16x8, b0v);
      bf16x8 pf1 = __builtin_bit_cast(bf16x8, b1v);

      // O^T += V^T * P^T  (A = vf frags); l via all-ones A-frag
#pragma unroll
      for (int dt = 0; dt < 4; dt++) {
        o[rh][dt] = __builtin_amdgcn_mfma_f32_16x16x32_bf16(vf0[dt], pf0, o[rh][dt], 0, 0, 0);
        o[rh][dt] = __builtin_amdgcn_mfma_f32_16x16x32_bf16(vf1[dt], pf1, o[rh][dt], 0, 0, 0);
      }
      ol[rh] = __builtin_amdgcn_mfma_f32_16x16x32_bf16(bones, pf0, ol[rh], 0, 0, 0);
      ol[rh] = __builtin_amdgcn_mfma_f32_16x16x32_bf16(bones, pf1, ol[rh], 0, 0, 0);
    }
  }

  // epilogue: lane holds O^T[d = dt*16+quad*4+r][q = qw+16rh+id16]; l = ol[rh][0]
#pragma unroll
  for (int rh = 0; rh < 2; rh++) {
    float inv = 1.0f / ol[rh][0];
    int qg = qw + 16 * rh + id16;
    u16* dst = Ob + (b * TT + qg) * CC + h * HDD + quad * 4;
#pragma unroll
    for (int dt = 0; dt < 4; dt++) {
      unsigned lo = ((unsigned)f2b(o[rh][dt][1] * inv) << 16) | f2b(o[rh][dt][0] * inv);
      unsigned hi = ((unsigned)f2b(o[rh][dt][3] * inv) << 16) | f2b(o[rh][dt][2] * inv);
      uint2 pairv; pairv.x = lo; pairv.y = hi;
      *(uint2*)(dst + dt * 16) = pairv;
    }
  }
}

extern "C" void kernel_launch(void* const* d_in, const int* in_sizes, int n_in,
                              void* d_out, int out_size, void* d_ws, size_t ws_size,
                              hipStream_t stream) {
  const float* x     = (const float*)d_in[0];
  const float* Wqkv  = (const float*)d_in[1];
  const float* bqkv  = (const float*)d_in[2];
  const float* Wproj = (const float*)d_in[3];
  const float* bproj = (const float*)d_in[4];
  // d_in[5] = start_pos (always 0; KV-cache write+slice is identity)
  float* out = (float*)d_out;

  u16* ws = (u16*)d_ws;
  u16* xb      = ws;                              // [4096 x 768]
  u16* Wqkv_t  = xb + BB * TT * CC;               // [2304 x 768]
  u16* Wproj_t = Wqkv_t + 3 * CC * CC;            // [768 x 768]
  u16* Qb      = Wproj_t + CC * CC;               // [BH][T][64]
  u16* Kb      = Qb + BHH * TT * HDD;             // [BH][T][64]
  u16* Vt      = Kb + BHH * TT * HDD;             // [BH][64][T]
  u16* Ob      = Vt + BHH * TT * HDD;             // [4096 x 768]

  k_prep<<<3072 + 1728, 256, 0, stream>>>(x, xb, Wqkv, Wqkv_t);
  k_qkv<<<32 * 24, 256, 0, stream>>>(xb, Wqkv_t, bqkv, Qb, Kb, Vt);
  k_attn<<<16 * BHH + 576, 128, 0, stream>>>(Qb, Kb, Vt, Ob, Wproj, Wproj_t);
  k_proj<<<64 * 8, 256, 0, stream>>>(Ob, Wproj_t, bproj, out);
}